// Round 14
// baseline (66202.661 us; speedup 1.0000x reference)
//
#include <hip/hip_runtime.h>
#include <hip/hip_fp16.h>
#include <math.h>

#define Tn 1024
#define Bn 256
#define Hn 120
#define Ln 4
#define BC 8                  // batch per block
#define NCH 32                // batch chunks (256/8)
#define NBLK (Ln*NCH)         // 128 blocks
#define RPT 15                // rows per thread (32 rowgroups x 15 = 480)
#define Dd 8                  // ring depth
#define PADI 32               // ints per flag -> one 128B line
#define KP 244                // LDS k-stride: 244%32=20 -> 8 batches hit 8 banks

// R14 RESTRUCTURE: shard over batch, not cells. Same-layer recurrence is
// IN-BLOCK (h in LDS fp32, zero cross-block RTT on the critical path).
// Cross-block deps: fan-in <= 2 (below-layer flag, feed-forward so detect
// ~0 in steady state; + Dd-slack consumer guard). Kills the 45-producer
// straggler-max that survived all R5-R13 micro-fixes.
// Proven primitives kept: sc0sc1 relaxed-system atomics (ring/flags),
// asm dwordx4 sc0sc1 staging, atomicExch publish, bounded spins + abort.
__device__ alignas(16) unsigned short g_ring[(size_t)3 * Dd * NCH * Hn * BC];
__device__ int g_prod[3 * NCH * PADI];   // layer l in 0..2 published thru t
__device__ int g_cons[Ln * NCH * PADI];  // layer l in 1..3 staged below thru t
__device__ int g_abort;

__global__ __launch_bounds__(256) void init_kernel() {
    int idx = blockIdx.x * 256 + threadIdx.x;
    if (idx < 3 * NCH)  g_prod[idx * PADI] = -1;
    if (idx < Ln * NCH) g_cons[idx * PADI] = -1;
    if (idx == 0)       g_abort = 0;
}

__device__ __forceinline__ float sigm(float v) { return 1.0f / (1.0f + expf(-v)); }

// Bounded spin on monotone flag with caller cache; first timeout sets the
// global abort (RMW) and marks the thread dead: wrong answer beats a dead
// container.
__device__ __forceinline__ void spin_wait(int* p, int tgt, int& dead, int& pc) {
    if (dead || pc >= tgt) return;
    int guard = 0, v;
    while ((v = __hip_atomic_load(p, __ATOMIC_RELAXED,
                                  __HIP_MEMORY_SCOPE_SYSTEM)) < tgt) {
        __builtin_amdgcn_s_sleep(1);
        if ((++guard & 127) == 0) {
            if (__hip_atomic_load(&g_abort, __ATOMIC_RELAXED,
                                  __HIP_MEMORY_SCOPE_SYSTEM)) { dead = 1; return; }
            if (guard > 60000) { atomicExch(&g_abort, 1); dead = 1; return; }
        }
    }
    pc = v;
}

// Block (l, bc): layer l, batches [bc*8, bc*8+8). Thread (rg=tid>>3, b=tid&7)
// computes gate rows rg*15..+15 for batch b. h(t) ring slot = t&7.
// Producer l<3 publishes prod=t after ring stores drain; consumer l>0 waits
// prod[l-1]>=t, stages, then publishes cons=t; producer at t>=8 waits
// cons[l+1] >= t-8 (slot overwrite guard).
__global__ __launch_bounds__(256, 1) void lstm_kernel(
    const float* __restrict__ x,    const float* __restrict__ h0,
    const float* __restrict__ c0,   const float* __restrict__ Wih0,
    const float* __restrict__ Wih,  const float* __restrict__ Whh,
    const float* __restrict__ bih,  const float* __restrict__ bhh,
    const float* __restrict__ Wlin, const float* __restrict__ blin,
    float* __restrict__ out)
{
    __shared__ alignas(16) float sh_hv[BC * KP];  // own-layer h, [b][k] fp32
    __shared__ alignas(16) float sh_hb[BC * KP];  // below-layer h, [b][k] fp32
    __shared__ float sh_g[480 * BC];              // gates [row][b]

    const int bx  = blockIdx.x;
    const int l   = bx >> 5;
    const int bc  = bx & 31;
    const int tid = threadIdx.x;
    const int b   = tid & 7;
    const int rg  = tid >> 3;
    const int row0 = rg * RPT;
    const int bg0  = bc * BC;
    int dead = 0, pcb = -0x40000000, pca = -0x40000000;

    float bias[RPT];
    #pragma unroll
    for (int r = 0; r < RPT; ++r)
        bias[r] = bih[l * 4 * Hn + row0 + r] + bhh[l * 4 * Hn + row0 + r];
    float w0[RPT];
    if (l == 0) {
        #pragma unroll
        for (int r = 0; r < RPT; ++r) w0[r] = Wih0[row0 + r];
    }

    // c-state in registers; own-h LDS init from h0. Items idx=cell*8+b.
    float cst[4] = {0.f, 0.f, 0.f, 0.f};
    #pragma unroll
    for (int j = 0; j < 4; ++j) {
        int idx = tid + 256 * j;
        if (idx < Hn * BC) {
            int cell = idx >> 3, bb = idx & 7;
            cst[j] = c0[(l * Bn + bg0 + bb) * Hn + cell];
            sh_hv[bb * KP + cell] = h0[(l * Bn + bg0 + bb) * Hn + cell];
        }
    }
    __syncthreads();

    const float* WhhL = Whh + (size_t)l * 4 * Hn * Hn;
    const float* WihL = (l > 0) ? Wih + (size_t)(l - 1) * 4 * Hn * Hn : Whh;
    unsigned short* ringP = g_ring + (size_t)l * Dd * NCH * Hn * BC;        // l<3 only
    const unsigned short* ringC =
        g_ring + (size_t)(l > 0 ? l - 1 : 0) * Dd * NCH * Hn * BC;

    for (int t = 0; t < Tn; ++t) {
        const int slot = t & (Dd - 1);

        if (l > 0 && tid == 0)
            spin_wait(&g_prod[((l - 1) * NCH + bc) * PADI], t, dead, pcb);
        if (l < 3 && t >= Dd && tid == 64)
            spin_wait(&g_cons[((l + 1) * NCH + bc) * PADI], t - Dd, dead, pca);
        __syncthreads();

        // issue below-h stage loads now; hide RTT behind the Whh phase
        uint4 vb = {0, 0, 0, 0};
        if (l > 0 && tid < Hn) {
            const unsigned short* p =
                ringC + ((size_t)slot * NCH + bc) * (Hn * BC) + tid * 8;
            asm volatile("global_load_dwordx4 %0, %1, off sc0 sc1"
                         : "=v"(vb) : "v"(p));
        }
        float xv = (l == 0) ? x[t * Bn + bg0 + b] : 0.f;

        float acc[RPT];
        #pragma unroll
        for (int r = 0; r < RPT; ++r) acc[r] = bias[r];
        if (l == 0) {
            #pragma unroll
            for (int r = 0; r < RPT; ++r) acc[r] = fmaf(w0[r], xv, acc[r]);
        }

        // phase 1: Whh over own h (LDS, fp32)
        for (int kb = 0; kb < Hn; kb += 4) {
            float4 hq = *(const float4*)&sh_hv[b * KP + kb];
            #pragma unroll
            for (int r = 0; r < RPT; ++r) {
                float4 wq = *(const float4*)&WhhL[(row0 + r) * Hn + kb];
                acc[r] = fmaf(wq.x, hq.x, fmaf(wq.y, hq.y,
                         fmaf(wq.z, hq.z, fmaf(wq.w, hq.w, acc[r]))));
            }
        }

        if (l > 0) {
            if (tid < Hn) {
                asm volatile("s_waitcnt vmcnt(0)" ::: "memory");
                unsigned u[4] = {vb.x, vb.y, vb.z, vb.w};
                #pragma unroll
                for (int i = 0; i < 4; ++i) {
                    sh_hb[(2 * i) * KP + tid] = __half2float(
                        __ushort_as_half((unsigned short)(u[i] & 0xffffu)));
                    sh_hb[(2 * i + 1) * KP + tid] = __half2float(
                        __ushort_as_half((unsigned short)(u[i] >> 16)));
                }
            }
            __syncthreads();
            if (tid == 32)
                atomicExch(&g_cons[(l * NCH + bc) * PADI], t);  // staged thru t
            // phase 2: Wih over below h
            for (int kb = 0; kb < Hn; kb += 4) {
                float4 hq = *(const float4*)&sh_hb[b * KP + kb];
                #pragma unroll
                for (int r = 0; r < RPT; ++r) {
                    float4 wq = *(const float4*)&WihL[(row0 + r) * Hn + kb];
                    acc[r] = fmaf(wq.x, hq.x, fmaf(wq.y, hq.y,
                             fmaf(wq.z, hq.z, fmaf(wq.w, hq.w, acc[r]))));
                }
            }
        }

        // gates -> LDS transpose
        #pragma unroll
        for (int r = 0; r < RPT; ++r) sh_g[(row0 + r) * BC + b] = acc[r];
        __syncthreads();

        // cell update: thread owns items idx=tid+256j (cell=idx>>3, b=idx&7)
        #pragma unroll
        for (int j = 0; j < 4; ++j) {
            int idx = tid + 256 * j;
            if (idx < Hn * BC) {
                int cell = idx >> 3, bb = idx & 7;
                float ig = sigm(sh_g[cell * BC + bb]);
                float fg = sigm(sh_g[(Hn + cell) * BC + bb]);
                float gg = tanhf(sh_g[(2 * Hn + cell) * BC + bb]);
                float og = sigm(sh_g[(3 * Hn + cell) * BC + bb]);
                float cn = fmaf(fg, cst[j], ig * gg);
                cst[j] = cn;
                float hn = og * tanhf(cn);
                sh_hv[bb * KP + cell] = hn;        // fp32 recurrence, in-block
                if (l < 3) {
                    unsigned short h16 = __half_as_ushort(__float2half(hn));
                    __hip_atomic_store(
                        &ringP[((size_t)slot * NCH + bc) * (Hn * BC) + idx],
                        h16, __ATOMIC_RELAXED, __HIP_MEMORY_SCOPE_SYSTEM);
                }
            }
        }

        if (l < 3) {
            asm volatile("s_waitcnt vmcnt(0)" ::: "memory");  // ring at MALL
            __syncthreads();
            if (tid == 0) atomicExch(&g_prod[(l * NCH + bc) * PADI], t);
        } else {
            __syncthreads();
            if (tid < BC) {   // exclusive batch slice: direct store, no atomics
                float pout = blin[0];
                for (int c = 0; c < Hn; ++c)
                    pout = fmaf(Wlin[c], sh_hv[tid * KP + c], pout);
                out[t * Bn + bg0 + tid] = pout;
            }
        }
    }
}

extern "C" void kernel_launch(void* const* d_in, const int* in_sizes, int n_in,
                              void* d_out, int out_size, void* d_ws, size_t ws_size,
                              hipStream_t stream) {
    const float* x    = (const float*)d_in[0];
    const float* h0   = (const float*)d_in[1];
    const float* c0   = (const float*)d_in[2];
    const float* Wih0 = (const float*)d_in[3];
    const float* Wih  = (const float*)d_in[4];
    const float* Whh  = (const float*)d_in[5];
    const float* bih  = (const float*)d_in[6];
    const float* bhh  = (const float*)d_in[7];
    const float* Wlin = (const float*)d_in[8];
    const float* blin = (const float*)d_in[9];
    float* out = (float*)d_out;

    hipLaunchKernelGGL(init_kernel, dim3(1), dim3(256), 0, stream);
    hipLaunchKernelGGL(lstm_kernel, dim3(NBLK), dim3(256), 0, stream,
                       x, h0, c0, Wih0, Wih, Whh, bih, bhh, Wlin, blin, out);
}

// Round 15
// 14306.865 us; speedup vs baseline: 4.6273x; 4.6273x over previous
//
#include <hip/hip_runtime.h>
#include <hip/hip_fp16.h>
#include <math.h>

#define Tn 1024
#define Bn 256
#define Hn 120
#define Ln 4
#define NBC 4                 // batch chunks of 64
#define NBLK (Ln*NBC)         // 16 blocks, one per (layer, bc)
#define THR 512               // 8 waves
#define Dd 8                  // ring depth
#define PADI 32
#define KPh 264               // hxT half-stride (16B-aligned rows)

typedef _Float16 f16x8 __attribute__((ext_vector_type(8)));
typedef float    f32x4 __attribute__((ext_vector_type(4)));
typedef unsigned short ushort_t;

// R15: MFMA persistent-cell kernel. One block per (layer, 64-batch):
// same-layer recurrence IN-BLOCK (hxT in LDS); weights resident in VGPRs
// as f16 A-fragments; gate rows pre-permuted to cell*4+gate so each
// lane's 4 C-regs are exactly (i,f,g,o) of one cell -> in-register cell
// update. Cross-block: fan-in 2 (below prod flag, above cons guard) via
// proven sc0sc1 primitives. f16 h/weights: R12/R13 proved fp16-ring
// absmax 2.4e-4 vs 3.2e-3 threshold.
__device__ ushort_t g_ring[(size_t)3 * Dd * NBC * 64 * Hn]; // [l][slot][bc][b][cell]
__device__ int g_prod[3 * NBC * PADI];
__device__ int g_cons[Ln * NBC * PADI];
__device__ int g_abort;

__global__ __launch_bounds__(256) void init_kernel() {
    int idx = threadIdx.x;
    if (idx < 3 * NBC)  g_prod[idx * PADI] = -1;
    if (idx < Ln * NBC) g_cons[idx * PADI] = -1;
    if (idx == 0)       g_abort = 0;
}

__device__ __forceinline__ float sigm(float v) { return 1.0f / (1.0f + expf(-v)); }

__device__ __forceinline__ void spin_wait(int* p, int tgt, int& dead, int& pc) {
    if (dead || pc >= tgt) return;
    int guard = 0, v;
    while ((v = __hip_atomic_load(p, __ATOMIC_RELAXED,
                                  __HIP_MEMORY_SCOPE_SYSTEM)) < tgt) {
        __builtin_amdgcn_s_sleep(1);
        if ((++guard & 127) == 0) {
            if (__hip_atomic_load(&g_abort, __ATOMIC_RELAXED,
                                  __HIP_MEMORY_SCOPE_SYSTEM)) { dead = 1; return; }
            if (guard > 60000) { atomicExch(&g_abort, 1); dead = 1; return; }
        }
    }
    pc = v;
}

// hx layout (LDS, f16): hxT[col=batch 0..63][k 0..255], k<120 = own h(t-1),
// k=120..239 = below h(t) (l>0) or k=120 = x(t) (l=0), rest zero-padded.
// GEMM: gates[480p x 64] = Wp[480p x K] * hx[K x 64], rows permuted
// r' = cell*4 + gate.
__global__ __launch_bounds__(THR, 2) void lstm_kernel(
    const float* __restrict__ x,    const float* __restrict__ h0,
    const float* __restrict__ c0,   const float* __restrict__ Wih0,
    const float* __restrict__ Wih,  const float* __restrict__ Whh,
    const float* __restrict__ bih,  const float* __restrict__ bhh,
    const float* __restrict__ Wlin, const float* __restrict__ blin,
    float* __restrict__ out)
{
    __shared__ _Float16 hxT[64 * KPh];   // 33.8 KB

    const int bx   = blockIdx.x;
    const int l    = bx >> 2;
    const int bc   = bx & 3;
    const int tid  = threadIdx.x;
    const int w    = tid >> 6;
    const int lane = tid & 63;
    const int quad = lane >> 4;
    const int l16  = lane & 15;
    const int bg0  = bc * 64;
    const int KTl  = (l == 0) ? 4 : 8;
    const int mtn  = (w < 6) ? 4 : 3;           // m-tiles this wave
    const int mt0  = (w < 6) ? 4 * w : 24 + 3 * (w - 6);
    int dead = 0, pcb = -0x40000000, pca = -0x40000000;

    const float* WhhL = Whh + (size_t)l * 4 * Hn * Hn;
    const float* WihL = (l > 0) ? Wih + (size_t)(l - 1) * 4 * Hn * Hn : Whh;
    ushort_t* ringP = g_ring + (size_t)l * Dd * NBC * 64 * Hn;          // l<3
    const ushort_t* ringC =
        g_ring + (size_t)(l > 0 ? l - 1 : 0) * Dd * NBC * 64 * Hn;

    // ---- persistent A-fragments (weights, f16) in VGPRs.
    // A[m=lane&15][k=quad*8+j]; permuted row r' -> orig row gate*Hn+cell.
    f16x8 a[4][8];
    #pragma unroll
    for (int m = 0; m < 4; ++m) {
        int rp = (mt0 + m) * 16 + l16;          // permuted row 0..479
        int cell = rp >> 2, gate = rp & 3;
        int orow = gate * Hn + cell;
        for (int kt = 0; kt < 8; ++kt) {
            f16x8 av;
            #pragma unroll
            for (int j = 0; j < 8; ++j) {
                int k = kt * 32 + quad * 8 + j;
                float v = 0.f;
                if (m < mtn) {
                    if (k < Hn)            v = WhhL[orow * Hn + k];
                    else if (l == 0)       v = (k == Hn) ? Wih0[orow] : 0.f;
                    else if (k < 2 * Hn)   v = WihL[orow * Hn + (k - Hn)];
                }
                av[j] = (_Float16)v;
            }
            a[m][kt] = av;
        }
    }

    // bias per (m, gate); c-state per (m, n)
    float bias_g[4][4];
    float cst[4][4];
    #pragma unroll
    for (int m = 0; m < 4; ++m) {
        int cell = (mt0 + m) * 4 + quad;
        #pragma unroll
        for (int g = 0; g < 4; ++g)
            bias_g[m][g] = (m < mtn)
                ? bih[l * 4 * Hn + g * Hn + cell] + bhh[l * 4 * Hn + g * Hn + cell]
                : 0.f;
        #pragma unroll
        for (int n = 0; n < 4; ++n) {
            int col = n * 16 + l16;
            cst[m][n] = (m < mtn) ? c0[(l * Bn + bg0 + col) * Hn + cell] : 0.f;
        }
    }

    // hxT init: own h from h0; zero k in [120,256)
    for (int q = tid; q < 64 * Hn; q += THR) {
        int col = q / Hn, cell = q % Hn;
        hxT[col * KPh + cell] = (_Float16)h0[(l * Bn + bg0 + col) * Hn + cell];
    }
    for (int q = tid; q < 64 * 136; q += THR) {
        int col = q / 136, kk = 120 + q % 136;
        hxT[col * KPh + kk] = (_Float16)0.f;
    }
    __syncthreads();

    for (int t = 0; t < Tn; ++t) {
        const int slot = t & (Dd - 1);

        if (l > 0 && tid == 0)
            spin_wait(&g_prod[((l - 1) * NBC + bc) * PADI], t, dead, pcb);
        if (l < 3 && t >= Dd && tid == 64)
            spin_wait(&g_cons[((l + 1) * NBC + bc) * PADI], t - Dd, dead, pca);
        __syncthreads();

        // ---- stage below-h (l>0) into hxT[.][120..240), raw f16 bits
        if (l > 0) {
            uint4 v0 = {0,0,0,0}, v1 = {0,0,0,0};
            int q0 = tid, q1 = tid + THR;       // 960 dwordx4 total
            const ushort_t* base = ringC + ((size_t)(slot * NBC + bc)) * 64 * Hn;
            if (q0 < 960) {
                const ushort_t* p = base + (q0 / 15) * Hn + (q0 % 15) * 8;
                asm volatile("global_load_dwordx4 %0, %1, off sc0 sc1"
                             : "=v"(v0) : "v"(p));
            }
            if (q1 < 960) {
                const ushort_t* p = base + (q1 / 15) * Hn + (q1 % 15) * 8;
                asm volatile("global_load_dwordx4 %0, %1, off sc0 sc1"
                             : "=v"(v1) : "v"(p));
            }
            asm volatile("s_waitcnt vmcnt(0)" ::: "memory");
            if (q0 < 960)
                *(uint4*)&hxT[(q0 / 15) * KPh + 120 + (q0 % 15) * 8] = v0;
            if (q1 < 960)
                *(uint4*)&hxT[(q1 / 15) * KPh + 120 + (q1 % 15) * 8] = v1;
        } else {
            if (tid < 64) hxT[tid * KPh + 120] = (_Float16)x[t * Bn + bg0 + tid];
        }
        __syncthreads();
        if (l > 0 && tid == 96)
            atomicExch(&g_cons[(l * NBC + bc) * PADI], t);   // staged thru t

        // ---- MFMA: acc[m][n] (+= bias)
        f32x4 acc[4][4];
        #pragma unroll
        for (int m = 0; m < 4; ++m)
            #pragma unroll
            for (int n = 0; n < 4; ++n) {
                f32x4 z; z[0] = bias_g[m][0]; z[1] = bias_g[m][1];
                z[2] = bias_g[m][2]; z[3] = bias_g[m][3];
                acc[m][n] = z;
            }
        for (int kt = 0; kt < KTl; ++kt) {
            f16x8 bfr[4];
            #pragma unroll
            for (int n = 0; n < 4; ++n)
                bfr[n] = *(const f16x8*)&hxT[(n * 16 + l16) * KPh + kt * 32 + quad * 8];
            #pragma unroll
            for (int m = 0; m < 4; ++m)
                if (m < mtn)
                    #pragma unroll
                    for (int n = 0; n < 4; ++n)
                        acc[m][n] = __builtin_amdgcn_mfma_f32_16x16x32_f16(
                            a[m][kt], bfr[n], acc[m][n], 0, 0, 0);
        }
        __syncthreads();   // all B reads done before h(t) overwrites hxT

        // ---- in-register cell update; lane owns (cell=(mt0+m)*4+quad, col)
        #pragma unroll
        for (int m = 0; m < 4; ++m) {
            if (m >= mtn) continue;
            int cell = (mt0 + m) * 4 + quad;
            #pragma unroll
            for (int n = 0; n < 4; ++n) {
                int col = n * 16 + l16;
                float ig = sigm(acc[m][n][0]);
                float fg = sigm(acc[m][n][1]);
                float gg = tanhf(acc[m][n][2]);
                float og = sigm(acc[m][n][3]);
                float cn = fmaf(fg, cst[m][n], ig * gg);
                cst[m][n] = cn;
                float hn = og * tanhf(cn);
                hxT[col * KPh + cell] = (_Float16)hn;
                if (l < 3) {
                    ushort_t bits = __half_as_ushort(__float2half(hn));
                    __hip_atomic_store(
                        &ringP[((size_t)(slot * NBC + bc) * 64 + col) * Hn + cell],
                        bits, __ATOMIC_RELAXED, __HIP_MEMORY_SCOPE_SYSTEM);
                }
            }
        }

        if (l < 3) {
            asm volatile("s_waitcnt vmcnt(0)" ::: "memory");  // ring at MALL
            __syncthreads();
            if (tid == 0) atomicExch(&g_prod[(l * NBC + bc) * PADI], t);
        } else {
            __syncthreads();   // h(t) in hxT complete
            if (tid < 64) {    // exclusive slice: direct store incl. bias
                float pout = blin[0];
                for (int c = 0; c < Hn; ++c)
                    pout = fmaf(Wlin[c], (float)hxT[tid * KPh + c], pout);
                out[t * Bn + bg0 + tid] = pout;
            }
        }
    }
}

extern "C" void kernel_launch(void* const* d_in, const int* in_sizes, int n_in,
                              void* d_out, int out_size, void* d_ws, size_t ws_size,
                              hipStream_t stream) {
    const float* x    = (const float*)d_in[0];
    const float* h0   = (const float*)d_in[1];
    const float* c0   = (const float*)d_in[2];
    const float* Wih0 = (const float*)d_in[3];
    const float* Wih  = (const float*)d_in[4];
    const float* Whh  = (const float*)d_in[5];
    const float* bih  = (const float*)d_in[6];
    const float* bhh  = (const float*)d_in[7];
    const float* Wlin = (const float*)d_in[8];
    const float* blin = (const float*)d_in[9];
    float* out = (float*)d_out;

    hipLaunchKernelGGL(init_kernel, dim3(1), dim3(256), 0, stream);
    hipLaunchKernelGGL(lstm_kernel, dim3(NBLK), dim3(THR), 0, stream,
                       x, h0, c0, Wih0, Wih, Whh, bih, bhh, Wlin, blin, out);
}